// Round 8
// baseline (518.965 us; speedup 1.0000x reference)
//
#include <hip/hip_runtime.h>

// Fused masked 3x3 conv x2 (MinkowskiConv stride-1 equivalent), fp32:
//   m = float(mask); h = relu((conv3x3(x*m,w1)+b1)*m); out = (conv3x3(h,w2)+b2)*m
//
// PURE-REGISTER row-rolling pipeline — no LDS, no __syncthreads — with a
// DISTANCE-2 software pipeline (3 rotating row buffers, statically named):
// the global loads for row k+2 are issued two full compute bodies (~600 cyc)
// before their first use, covering HBM/L2 latency under load.
// Each lane owns 4 consecutive columns; a wave owns a 256-col band and
// sweeps 20 x-rows to emit 16 output rows. Horizontal 3-tap halos via 2
// lane-shuffles per conv; band-edge halo via ONE shared 8B load slot
// (lane 0 loads cols a-2..a-1, lane 63 loads a+256..a+257 — mutually
// exclusive, so they share registers). Vertical 3-taps roll through P/Q
// (conv1) and R/S (conv2). Image boundaries fall out naturally: OOB rows
// load zeros and rolled mask registers are 0 outside the image.

#define IMG_W 2048
#define IMG_H 2048
#define BAND  256          // columns per wave (8 bands exactly cover W)
#define RPW   16           // output rows per wave
#define ITERS (RPW + 4)    // 20: pipeline depth 4 (2 prime conv1, 2 conv2)

struct RowIn {
    float4 xv; int4 mv;    // this lane's 4 cols          (8 VGPR)
    float2 ed; int2 edm;   // edge cols: lane0 = a-2,a-1; lane63 = a+256,a+257 (4 VGPR)
};

__global__ __launch_bounds__(256, 8) void fused_mconv2_reg(
    const float* __restrict__ x, const int* __restrict__ mask,
    const float* __restrict__ w1p, const float* __restrict__ b1p,
    const float* __restrict__ w2p, const float* __restrict__ b2p,
    float* __restrict__ out)
{
    const int lane = threadIdx.x;                          // 0..63
    const int t0   = blockIdx.y * (4 * RPW) + threadIdx.y * RPW;
    const int a    = blockIdx.x * BAND;                    // band start col
    const int col  = a + (lane << 2);                      // this lane's 4 cols
    const size_t plane = (size_t)IMG_W * IMG_H;
    const float* xb = x    + (size_t)blockIdx.z * plane;
    const int*   mb = mask + (size_t)blockIdx.z * plane;
    float*       ob = out  + (size_t)blockIdx.z * plane;

    float W1[9], W2[9];                    // wave-uniform -> SGPRs
    #pragma unroll
    for (int i = 0; i < 9; ++i) { W1[i] = w1p[i]; W2[i] = w2p[i]; }
    const float B1 = b1p[0], B2 = b2p[0];

    const bool eL = (lane == 0)  && (a > 0);
    const bool eR = (lane == 63) && (a + BAND < IMG_W);
    const bool hasE = eL || eR;
    const int  ecol = eL ? (a - 2) : (a + BAND);

    // rolling state
    float P[4] = {0,0,0,0}, Q[4] = {0,0,0,0};     // conv1 vertical roll
    float R[4] = {0,0,0,0}, S[4] = {0,0,0,0};     // conv2 vertical roll
    float PE = 0, QE = 0, PR = 0, QR = 0;         // conv1 roll, edge cols
    float mfp[4] = {0,0,0,0}, mfq[4] = {0,0,0,0}; // mask rows s-1, s-2
    float mfEp = 0.f, mfRp = 0.f;                 // edge-col masks, row s-1

    auto load_row = [&](int k, RowIn& r) {
        r.xv = make_float4(0.f, 0.f, 0.f, 0.f);
        r.mv = make_int4(0, 0, 0, 0);
        r.ed = make_float2(0.f, 0.f); r.edm = make_int2(0, 0);
        const int s = t0 - 2 + k;
        if (s >= 0 && s < IMG_H) {                // wave-uniform
            const size_t ro = (size_t)s * IMG_W;
            r.xv = *reinterpret_cast<const float4*>(xb + ro + col);
            r.mv = *reinterpret_cast<const int4*>(mb + ro + col);
            if (hasE) {                           // only lanes 0 / 63
                r.ed  = *reinterpret_cast<const float2*>(xb + ro + ecol);
                r.edm = *reinterpret_cast<const int2*>(mb + ro + ecol);
            }
        }
    };

    auto compute = [&](const RowIn& r, int k) {
        const int s = t0 - 2 + k;
        const float e0  = r.ed.x * (float)r.edm.x;   // xm at a-2 (L) / a+256 (R)
        const float e1  = r.ed.y * (float)r.edm.y;   // xm at a-1 (L) / a+257 (R)
        const float mfE = (float)r.edm.y;            // mask at a-1  (lane 0)
        const float mfR = (float)r.edm.x;            // mask at a+256 (lane 63)
        float mf[4] = {(float)r.mv.x, (float)r.mv.y, (float)r.mv.z, (float)r.mv.w};
        float t_[6];                              // xm window: cols col-1..col+4
        t_[1] = r.xv.x * mf[0];  t_[2] = r.xv.y * mf[1];
        t_[3] = r.xv.z * mf[2];  t_[4] = r.xv.w * mf[3];
        const float upx = __shfl_up(t_[4], 1);
        const float dnx = __shfl_down(t_[1], 1);
        t_[0] = (lane == 0)  ? e1 : upx;          // xm(col-1); 0 at image edge
        t_[5] = (lane == 63) ? e0 : dnx;          // xm(col+4)

        // ---- conv1 dots + vertical roll: hm row s-1 ----
        float hm[4];
        #pragma unroll
        for (int c = 0; c < 4; ++c) {
            const float u0 = W1[0]*t_[c] + W1[1]*t_[c+1] + W1[2]*t_[c+2];
            const float u1 = W1[3]*t_[c] + W1[4]*t_[c+1] + W1[5]*t_[c+2];
            const float u2 = W1[6]*t_[c] + W1[7]*t_[c+1] + W1[8]*t_[c+2];
            const float h  = Q[c] + u2 + B1;      // h(s-1, col+c) pre-mask
            hm[c] = fmaxf(h, 0.f) * mfp[c];
            Q[c] = P[c] + u1;
            P[c] = u0;
        }
        // edge col a-1 (lane 0): taps e0, e1, t_[1]
        float hmE, hmRv;
        {
            const float u0 = W1[0]*e0 + W1[1]*e1 + W1[2]*t_[1];
            const float u1 = W1[3]*e0 + W1[4]*e1 + W1[5]*t_[1];
            const float u2 = W1[6]*e0 + W1[7]*e1 + W1[8]*t_[1];
            const float h  = QE + u2 + B1;
            hmE = fmaxf(h, 0.f) * mfEp;
            QE = PE + u1;  PE = u0;
        }
        // edge col a+256 (lane 63): taps t_[4], e0, e1
        {
            const float u0 = W1[0]*t_[4] + W1[1]*e0 + W1[2]*e1;
            const float u1 = W1[3]*t_[4] + W1[4]*e0 + W1[5]*e1;
            const float u2 = W1[6]*t_[4] + W1[7]*e0 + W1[8]*e1;
            const float h  = QR + u2 + B1;
            hmRv = fmaxf(h, 0.f) * mfRp;
            QR = PR + u1;  PR = u0;
        }

        // ---- conv2 on hm row s-1 ----
        float g_[6];
        g_[1] = hm[0]; g_[2] = hm[1]; g_[3] = hm[2]; g_[4] = hm[3];
        const float uph = __shfl_up(hm[3], 1);
        const float dnh = __shfl_down(hm[0], 1);
        g_[0] = (lane == 0)  ? hmE  : uph;
        g_[5] = (lane == 63) ? hmRv : dnh;

        float v0[4], v1[4], v2[4];
        #pragma unroll
        for (int c = 0; c < 4; ++c) {
            v0[c] = W2[0]*g_[c] + W2[1]*g_[c+1] + W2[2]*g_[c+2];
            v1[c] = W2[3]*g_[c] + W2[4]*g_[c+1] + W2[5]*g_[c+2];
            v2[c] = W2[6]*g_[c] + W2[7]*g_[c+1] + W2[8]*g_[c+2];
        }
        if (k >= 4) {                             // out row s-2
            float4 o;
            o.x = (S[0] + v2[0] + B2) * mfq[0];
            o.y = (S[1] + v2[1] + B2) * mfq[1];
            o.z = (S[2] + v2[2] + B2) * mfq[2];
            o.w = (S[3] + v2[3] + B2) * mfq[3];
            *reinterpret_cast<float4*>(ob + (size_t)(s - 2) * IMG_W + col) = o;
        }
        #pragma unroll
        for (int c = 0; c < 4; ++c) { S[c] = R[c] + v1[c]; R[c] = v0[c]; }
        #pragma unroll
        for (int c = 0; c < 4; ++c) { mfq[c] = mfp[c]; mfp[c] = mf[c]; }
        mfEp = mfE;  mfRp = mfR;
    };

    // distance-2 pipeline: at top of each iter, A holds row k, B row k+1;
    // C's load (row k+2) issues ~2 compute bodies before its use.
    RowIn A, Bv, C;
    load_row(0, A);
    load_row(1, Bv);
    #pragma unroll 1
    for (int k = 0; k < ITERS; k += 3) {
        if (k + 2 < ITERS) load_row(k + 2, C);
        compute(A, k);
        if (k + 3 < ITERS) load_row(k + 3, A);
        if (k + 1 < ITERS) compute(Bv, k + 1);
        if (k + 4 < ITERS) load_row(k + 4, Bv);
        if (k + 2 < ITERS) compute(C, k + 2);
    }
}

extern "C" void kernel_launch(void* const* d_in, const int* in_sizes, int n_in,
                              void* d_out, int out_size, void* d_ws, size_t ws_size,
                              hipStream_t stream) {
    const float* x    = (const float*)d_in[0];
    const int*   mask = (const int*)  d_in[1];
    const float* w1   = (const float*)d_in[2];
    const float* b1   = (const float*)d_in[3];
    const float* w2   = (const float*)d_in[4];
    const float* b2   = (const float*)d_in[5];
    float*       out  = (float*)d_out;

    const int B = in_sizes[0] / (IMG_W * IMG_H);

    dim3 block(64, 4, 1);                            // 4 independent waves
    dim3 grid(IMG_W / BAND, IMG_H / (4 * RPW), B);   // 8 x 32 x 8 = 2048 blocks
    hipLaunchKernelGGL(fused_mconv2_reg, grid, block, 0, stream,
                       x, mask, w1, b1, w2, b2, out);
}

// Round 9
// 94.906 us; speedup vs baseline: 5.4682x; 5.4682x over previous
//
#include <hip/hip_runtime.h>

// Fused masked 3x3 conv x2 (MinkowskiConv stride-1 equivalent), fp32:
//   m = float(mask); h = relu((conv3x3(x*m,w1)+b1)*m); out = (conv3x3(h,w2)+b2)*m
//
// PURE-REGISTER row-rolling pipeline — no LDS, no __syncthreads — with a
// DISTANCE-2 software pipeline (3 rotating, statically-named row buffers).
// CRITICAL: all global loads are BRANCH-FREE (clamped addresses + 0/1
// validity multipliers) so the compiler can statically count outstanding
// VMEM ops and emit counted vmcnt waits — conditional loads force
// conservative vmcnt(0) and kill the pipeline.
// Each lane owns 4 consecutive columns; a wave owns a 256-col band and
// sweeps 20 x-rows to emit 16 output rows. Horizontal 3-tap halos via 2
// lane-shuffles per conv; band-edge halo via one 8B slot loaded by ALL
// lanes (lanes 1..62 hit their own already-fetched line in L1; only
// lanes 0/63 consume it). Vertical 3-taps roll through P/Q (conv1) and
// R/S (conv2). Image boundaries: rowvalid/edge-valid flags zero the mask
// outside the image, which zeroes xm and the output mask.

#define IMG_W 2048
#define IMG_H 2048
#define BAND  256          // columns per wave (8 bands exactly cover W)
#define RPW   16           // output rows per wave
#define ITERS (RPW + 4)    // 20: pipeline depth 4 (2 prime conv1, 2 conv2)

struct RowIn {
    float4 xv; int4 mv;    // this lane's 4 cols            (8 VGPR)
    float2 ed; int2 edm;   // edge slot (lanes 0/63 meaningful) (4 VGPR)
};

__global__ __launch_bounds__(256) void fused_mconv2_reg(
    const float* __restrict__ x, const int* __restrict__ mask,
    const float* __restrict__ w1p, const float* __restrict__ b1p,
    const float* __restrict__ w2p, const float* __restrict__ b2p,
    float* __restrict__ out)
{
    const int lane = threadIdx.x;                          // 0..63
    const int t0   = blockIdx.y * (4 * RPW) + threadIdx.y * RPW;
    const int a    = blockIdx.x * BAND;                    // band start col
    const int col  = a + (lane << 2);                      // this lane's 4 cols
    const size_t plane = (size_t)IMG_W * IMG_H;
    const float* xb = x    + (size_t)blockIdx.z * plane;
    const int*   mb = mask + (size_t)blockIdx.z * plane;
    float*       ob = out  + (size_t)blockIdx.z * plane;

    float W1[9], W2[9];
    #pragma unroll
    for (int i = 0; i < 9; ++i) { W1[i] = w1p[i]; W2[i] = w2p[i]; }
    const float B1 = b1p[0], B2 = b2p[0];

    // branch-free edge-slot address + validity (per-lane constants)
    int ecol = col;
    if (lane == 0)  ecol = (a > 0) ? (a - 2) : 0;
    if (lane == 63) ecol = (a + BAND < IMG_W) ? (a + BAND) : (IMG_W - 2);
    const float eVal = ((lane == 0 && a > 0) ||
                       (lane == 63 && a + BAND < IMG_W)) ? 1.f : 0.f;

    // rolling state
    float P[4] = {0,0,0,0}, Q[4] = {0,0,0,0};     // conv1 vertical roll
    float R[4] = {0,0,0,0}, S[4] = {0,0,0,0};     // conv2 vertical roll
    float PE = 0, QE = 0, PR = 0, QR = 0;         // conv1 roll, edge cols
    float mfp[4] = {0,0,0,0}, mfq[4] = {0,0,0,0}; // mask rows s-1, s-2
    float mfEp = 0.f, mfRp = 0.f;                 // edge-col masks, row s-1

    auto load_row = [&](int k, RowIn& r) {        // BRANCH-FREE: 4 VMEM, always
        const int s  = t0 - 2 + k;
        const int sc = s < 0 ? 0 : (s >= IMG_H ? IMG_H - 1 : s);
        const size_t ro = (size_t)sc * IMG_W;
        r.xv  = *reinterpret_cast<const float4*>(xb + ro + col);
        r.mv  = *reinterpret_cast<const int4*>(mb + ro + col);
        r.ed  = *reinterpret_cast<const float2*>(xb + ro + ecol);
        r.edm = *reinterpret_cast<const int2*>(mb + ro + ecol);
    };

    auto compute = [&](const RowIn& r, int k) {
        const int s = t0 - 2 + k;
        const float rv = (s >= 0 && s < IMG_H) ? 1.f : 0.f;   // wave-uniform
        const float ev = eVal * rv;
        const float e0  = r.ed.x * (float)r.edm.x * ev;  // xm at a-2 (L) / a+256 (R)
        const float e1  = r.ed.y * (float)r.edm.y * ev;  // xm at a-1 (L) / a+257 (R)
        const float mfE = (float)r.edm.y * ev;           // mask at a-1   (lane 0)
        const float mfR = (float)r.edm.x * ev;           // mask at a+256 (lane 63)
        float mf[4] = {rv * (float)r.mv.x, rv * (float)r.mv.y,
                       rv * (float)r.mv.z, rv * (float)r.mv.w};
        float t_[6];                              // xm window: cols col-1..col+4
        t_[1] = r.xv.x * mf[0];  t_[2] = r.xv.y * mf[1];
        t_[3] = r.xv.z * mf[2];  t_[4] = r.xv.w * mf[3];
        const float upx = __shfl_up(t_[4], 1);
        const float dnx = __shfl_down(t_[1], 1);
        t_[0] = (lane == 0)  ? e1 : upx;          // xm(col-1); 0 at image edge
        t_[5] = (lane == 63) ? e0 : dnx;          // xm(col+4)

        // ---- conv1 dots + vertical roll: hm row s-1 ----
        float hm[4];
        #pragma unroll
        for (int c = 0; c < 4; ++c) {
            const float u0 = W1[0]*t_[c] + W1[1]*t_[c+1] + W1[2]*t_[c+2];
            const float u1 = W1[3]*t_[c] + W1[4]*t_[c+1] + W1[5]*t_[c+2];
            const float u2 = W1[6]*t_[c] + W1[7]*t_[c+1] + W1[8]*t_[c+2];
            const float h  = Q[c] + u2 + B1;      // h(s-1, col+c) pre-mask
            hm[c] = fmaxf(h, 0.f) * mfp[c];
            Q[c] = P[c] + u1;
            P[c] = u0;
        }
        // edge col a-1 (lane 0): taps e0, e1, t_[1]
        float hmE, hmRv;
        {
            const float u0 = W1[0]*e0 + W1[1]*e1 + W1[2]*t_[1];
            const float u1 = W1[3]*e0 + W1[4]*e1 + W1[5]*t_[1];
            const float u2 = W1[6]*e0 + W1[7]*e1 + W1[8]*t_[1];
            const float h  = QE + u2 + B1;
            hmE = fmaxf(h, 0.f) * mfEp;
            QE = PE + u1;  PE = u0;
        }
        // edge col a+256 (lane 63): taps t_[4], e0, e1
        {
            const float u0 = W1[0]*t_[4] + W1[1]*e0 + W1[2]*e1;
            const float u1 = W1[3]*t_[4] + W1[4]*e0 + W1[5]*e1;
            const float u2 = W1[6]*t_[4] + W1[7]*e0 + W1[8]*e1;
            const float h  = QR + u2 + B1;
            hmRv = fmaxf(h, 0.f) * mfRp;
            QR = PR + u1;  PR = u0;
        }

        // ---- conv2 on hm row s-1 ----
        float g_[6];
        g_[1] = hm[0]; g_[2] = hm[1]; g_[3] = hm[2]; g_[4] = hm[3];
        const float uph = __shfl_up(hm[3], 1);
        const float dnh = __shfl_down(hm[0], 1);
        g_[0] = (lane == 0)  ? hmE  : uph;
        g_[5] = (lane == 63) ? hmRv : dnh;

        float v0[4], v1[4], v2[4];
        #pragma unroll
        for (int c = 0; c < 4; ++c) {
            v0[c] = W2[0]*g_[c] + W2[1]*g_[c+1] + W2[2]*g_[c+2];
            v1[c] = W2[3]*g_[c] + W2[4]*g_[c+1] + W2[5]*g_[c+2];
            v2[c] = W2[6]*g_[c] + W2[7]*g_[c+1] + W2[8]*g_[c+2];
        }
        if (k >= 4) {                             // out row s-2
            float4 o;
            o.x = (S[0] + v2[0] + B2) * mfq[0];
            o.y = (S[1] + v2[1] + B2) * mfq[1];
            o.z = (S[2] + v2[2] + B2) * mfq[2];
            o.w = (S[3] + v2[3] + B2) * mfq[3];
            *reinterpret_cast<float4*>(ob + (size_t)(s - 2) * IMG_W + col) = o;
        }
        #pragma unroll
        for (int c = 0; c < 4; ++c) { S[c] = R[c] + v1[c]; R[c] = v0[c]; }
        #pragma unroll
        for (int c = 0; c < 4; ++c) { mfq[c] = mfp[c]; mfp[c] = mf[c]; }
        mfEp = mfE;  mfRp = mfR;
    };

    // distance-2 pipeline: loads for row k+2 issue two compute bodies early
    RowIn A, Bv, C;
    load_row(0, A);
    load_row(1, Bv);
    #pragma unroll 1
    for (int k = 0; k < ITERS; k += 3) {
        if (k + 2 < ITERS) load_row(k + 2, C);
        compute(A, k);
        if (k + 3 < ITERS) load_row(k + 3, A);
        if (k + 1 < ITERS) compute(Bv, k + 1);
        if (k + 4 < ITERS) load_row(k + 4, Bv);
        if (k + 2 < ITERS) compute(C, k + 2);
    }
}

extern "C" void kernel_launch(void* const* d_in, const int* in_sizes, int n_in,
                              void* d_out, int out_size, void* d_ws, size_t ws_size,
                              hipStream_t stream) {
    const float* x    = (const float*)d_in[0];
    const int*   mask = (const int*)  d_in[1];
    const float* w1   = (const float*)d_in[2];
    const float* b1   = (const float*)d_in[3];
    const float* w2   = (const float*)d_in[4];
    const float* b2   = (const float*)d_in[5];
    float*       out  = (float*)d_out;

    const int B = in_sizes[0] / (IMG_W * IMG_H);

    dim3 block(64, 4, 1);                            // 4 independent waves
    dim3 grid(IMG_W / BAND, IMG_H / (4 * RPW), B);   // 8 x 32 x 8 = 2048 blocks
    hipLaunchKernelGGL(fused_mconv2_reg, grid, block, 0, stream,
                       x, mask, w1, b1, w2, b2, out);
}

// Round 10
// 91.763 us; speedup vs baseline: 5.6555x; 1.0343x over previous
//
#include <hip/hip_runtime.h>

// Fused masked 3x3 conv x2 (MinkowskiConv stride-1 equivalent), fp32:
//   m = float(mask); h = relu((conv3x3(x*m,w1)+b1)*m); out = (conv3x3(h,w2)+b2)*m
//
// HYBRID: LDS-staged inputs + register-rolling compute.
//  - Stage x*m (float, [20][264]) and mask (bytes, [18][264]) for a 256x16
//    output tile; one __syncthreads; then each of 4 waves rolls over its own
//    4 output rows (8 iters: 4 prime, 4 emit).
//  - Per row-iter per lane: ONE ds_read_b128 (own 4 cols, 16B-stride pure
//    saturation, no conflict), 2 uniform-address edge reads (broadcast),
//    1 u32 mask read (4B stride, conflict-free), 2 shuffles per conv for
//    the horizontal halo. h never touches LDS.
//  - Vertical 3-taps roll through P/Q (conv1) and R/S (conv2) registers;
//    serial-chain feed latency is LDS (~120cy), hidden by 24 waves/CU.
// Boundary handling: out-of-image staging writes 0 (mask 0 -> xm 0), so
// edge h/out values are correct by construction.

#define IMG_W 2048
#define IMG_H 2048
#define TB_W  256          // output tile width  (one wave: 64 lanes x 4 cols)
#define TB_H  16           // output tile height (4 waves x 4 rows)
#define SX    264          // staged cols: image a-4 .. a+259
#define SY    20           // staged rows: r0-2 .. r0+17
#define MY    18           // mask rows:   r0-1 .. r0+16
#define NCH   (SX / 4)     // 66 float4 chunks per staged row
#define NSTG  (SY * NCH)   // 1320

__global__ __launch_bounds__(256) void fused_mconv2_hyb(
    const float* __restrict__ x, const int* __restrict__ mask,
    const float* __restrict__ w1p, const float* __restrict__ b1p,
    const float* __restrict__ w2p, const float* __restrict__ b2p,
    float* __restrict__ out)
{
    __shared__ __align__(16) float s_xm[SY][SX];
    __shared__ __align__(4)  unsigned char s_m[MY][SX];

    const int lane = threadIdx.x;            // 0..63
    const int wv   = threadIdx.y;            // 0..3
    const int tid  = wv * 64 + lane;
    const int a    = blockIdx.x * TB_W;
    const int r0   = blockIdx.y * TB_H;
    const size_t plane = (size_t)IMG_W * IMG_H;
    const float* xb = x    + (size_t)blockIdx.z * plane;
    const int*   mb = mask + (size_t)blockIdx.z * plane;
    float*       ob = out  + (size_t)blockIdx.z * plane;

    float W1[9], W2[9];
    #pragma unroll
    for (int i = 0; i < 9; ++i) { W1[i] = w1p[i]; W2[i] = w2p[i]; }
    const float B1 = b1p[0], B2 = b2p[0];

    // ---- stage x*m (float4) + mask bytes, origin (r0-2, a-4) ----
    for (int idx = tid; idx < NSTG; idx += 256) {
        const int row = idx / NCH;
        const int k4  = idx - row * NCH;
        const int r   = r0 - 2 + row;
        const int c   = a - 4 + (k4 << 2);
        float4 xm = make_float4(0.f, 0.f, 0.f, 0.f);
        unsigned mpack = 0u;
        if (r >= 0 && r < IMG_H && c >= 0 && c < IMG_W) {  // all-or-nothing 16B
            const size_t g = (size_t)r * IMG_W + c;
            const float4 xv = *reinterpret_cast<const float4*>(xb + g);
            const int4   mi = *reinterpret_cast<const int4*>(mb + g);
            xm.x = mi.x ? xv.x : 0.f;
            xm.y = mi.y ? xv.y : 0.f;
            xm.z = mi.z ? xv.z : 0.f;
            xm.w = mi.w ? xv.w : 0.f;
            mpack = (unsigned)mi.x | ((unsigned)mi.y << 8) |
                    ((unsigned)mi.z << 16) | ((unsigned)mi.w << 24);
        }
        *reinterpret_cast<float4*>(&s_xm[row][k4 << 2]) = xm;
        if (row >= 1 && row <= MY)                        // mask rows r0-1..r0+16
            *reinterpret_cast<unsigned*>(&s_m[row - 1][k4 << 2]) = mpack;
    }
    __syncthreads();

    // ---- per-wave register rolling over 4 output rows (8 iters) ----
    // Wave wv consumes stage rows 4wv..4wv+7 (image rows r0-2+4wv+t).
    // Iter t: hm = masked-relu h of image row s-1; emit out row s-2 at t>=4.
    const int cbase = (lane << 2) + 4;       // lane's b128 stage-col base
    float P[4] = {0,0,0,0}, Q[4] = {0,0,0,0};
    float R[4] = {0,0,0,0}, S[4] = {0,0,0,0};
    float PE = 0, QE = 0, PR = 0, QR = 0;    // edge-col (h -1 / h 256) chains
    float mq[4] = {0,0,0,0};                 // mask row s-2 (for emit)

    #pragma unroll
    for (int t = 0; t < 8; ++t) {
        const int srow = (wv << 2) + t;                       // 0..19
        const float4 xv  = *reinterpret_cast<const float4*>(&s_xm[srow][cbase]);
        const float2 eLx = *reinterpret_cast<const float2*>(&s_xm[srow][2]);   // cols 2,3
        const float2 eRx = *reinterpret_cast<const float2*>(&s_xm[srow][260]); // cols 260,261
        int mi_ = (wv << 2) + t - 2;                          // mask row of s-1
        mi_ = mi_ < 0 ? 0 : mi_;                              // clamp (garbage iters)
        const unsigned mw  = *reinterpret_cast<const unsigned*>(&s_m[mi_][cbase]);
        const unsigned mwL = *reinterpret_cast<const unsigned*>(&s_m[mi_][0]);
        const unsigned mwR = *reinterpret_cast<const unsigned*>(&s_m[mi_][260]);
        float mf[4];
        mf[0] = (float)(mw & 255u);         mf[1] = (float)((mw >> 8) & 255u);
        mf[2] = (float)((mw >> 16) & 255u); mf[3] = (float)((mw >> 24) & 255u);
        const float mEL = (float)((mwL >> 24) & 255u);        // m at stage col 3 (h col -1)
        const float mER = (float)(mwR & 255u);                // m at stage col 260 (h col 256)

        float t_[6];                          // xm taps: stage cols 4c+3 .. 4c+8
        t_[1] = xv.x; t_[2] = xv.y; t_[3] = xv.z; t_[4] = xv.w;
        const float upx = __shfl_up(xv.w, 1);
        const float dnx = __shfl_down(xv.x, 1);
        t_[0] = (lane == 0)  ? eLx.y : upx;
        t_[5] = (lane == 63) ? eRx.x : dnx;

        // conv1 dots + vertical roll: hm = masked relu of h row s-1
        float hm[4];
        #pragma unroll
        for (int c = 0; c < 4; ++c) {
            const float u0 = W1[0]*t_[c] + W1[1]*t_[c+1] + W1[2]*t_[c+2];
            const float u1 = W1[3]*t_[c] + W1[4]*t_[c+1] + W1[5]*t_[c+2];
            const float u2 = W1[6]*t_[c] + W1[7]*t_[c+1] + W1[8]*t_[c+2];
            const float h  = Q[c] + u2 + B1;
            hm[c] = fmaxf(h, 0.f) * mf[c];
            Q[c] = P[c] + u1;
            P[c] = u0;
        }
        // edge h col -1 (lane 0): taps stage cols 2,3,4 = eLx.x, eLx.y, xv.x
        float hmE, hmRv;
        {
            const float u0 = W1[0]*eLx.x + W1[1]*eLx.y + W1[2]*xv.x;
            const float u1 = W1[3]*eLx.x + W1[4]*eLx.y + W1[5]*xv.x;
            const float u2 = W1[6]*eLx.x + W1[7]*eLx.y + W1[8]*xv.x;
            const float h  = QE + u2 + B1;
            hmE = fmaxf(h, 0.f) * mEL;
            QE = PE + u1;  PE = u0;
        }
        // edge h col 256 (lane 63): taps stage cols 259,260,261 = xv.w, eRx.x, eRx.y
        {
            const float u0 = W1[0]*xv.w + W1[1]*eRx.x + W1[2]*eRx.y;
            const float u1 = W1[3]*xv.w + W1[4]*eRx.x + W1[5]*eRx.y;
            const float u2 = W1[6]*xv.w + W1[7]*eRx.x + W1[8]*eRx.y;
            const float h  = QR + u2 + B1;
            hmRv = fmaxf(h, 0.f) * mER;
            QR = PR + u1;  PR = u0;
        }

        // conv2 on hm row s-1
        float g_[6];
        g_[1] = hm[0]; g_[2] = hm[1]; g_[3] = hm[2]; g_[4] = hm[3];
        const float uph = __shfl_up(hm[3], 1);
        const float dnh = __shfl_down(hm[0], 1);
        g_[0] = (lane == 0)  ? hmE  : uph;
        g_[5] = (lane == 63) ? hmRv : dnh;

        float v0[4], v1[4], v2[4];
        #pragma unroll
        for (int c = 0; c < 4; ++c) {
            v0[c] = W2[0]*g_[c] + W2[1]*g_[c+1] + W2[2]*g_[c+2];
            v1[c] = W2[3]*g_[c] + W2[4]*g_[c+1] + W2[5]*g_[c+2];
            v2[c] = W2[6]*g_[c] + W2[7]*g_[c+1] + W2[8]*g_[c+2];
        }
        if (t >= 4) {                        // emit out row r0 + 4*wv + t - 4
            const int orow = r0 + (wv << 2) + t - 4;
            float4 o;
            o.x = (S[0] + v2[0] + B2) * mq[0];
            o.y = (S[1] + v2[1] + B2) * mq[1];
            o.z = (S[2] + v2[2] + B2) * mq[2];
            o.w = (S[3] + v2[3] + B2) * mq[3];
            *reinterpret_cast<float4*>(ob + (size_t)orow * IMG_W + (a + (lane << 2))) = o;
        }
        #pragma unroll
        for (int c = 0; c < 4; ++c) { S[c] = R[c] + v1[c]; R[c] = v0[c]; }
        #pragma unroll
        for (int c = 0; c < 4; ++c) { mq[c] = mf[c]; }
    }
}

extern "C" void kernel_launch(void* const* d_in, const int* in_sizes, int n_in,
                              void* d_out, int out_size, void* d_ws, size_t ws_size,
                              hipStream_t stream) {
    const float* x    = (const float*)d_in[0];
    const int*   mask = (const int*)  d_in[1];
    const float* w1   = (const float*)d_in[2];
    const float* b1   = (const float*)d_in[3];
    const float* w2   = (const float*)d_in[4];
    const float* b2   = (const float*)d_in[5];
    float*       out  = (float*)d_out;

    const int B = in_sizes[0] / (IMG_W * IMG_H);

    dim3 block(64, 4, 1);
    dim3 grid(IMG_W / TB_W, IMG_H / TB_H, B);   // 8 x 128 x 8 = 8192 blocks
    hipLaunchKernelGGL(fused_mconv2_hyb, grid, block, 0, stream,
                       x, mask, w1, b1, w2, b2, out);
}

// Round 11
// 81.748 us; speedup vs baseline: 6.3483x; 1.1225x over previous
//
#include <hip/hip_runtime.h>

// Fused masked 3x3 conv x2 (MinkowskiConv stride-1 equivalent), fp32:
//   m   = float(mask)
//   h   = relu((conv3x3(x*m, w1) + b1) * m)
//   out = (conv3x3(h, w2) + b2) * m
// Round-3 structure (best measured: LDS-tiled, enc-sign mask folding,
// conflict-free b32 access, conv2 vertical register rolling) + ONE change:
// NON-TEMPORAL output stores. The output (128 MB, never re-read) was
// allocating into the 256 MB Infinity Cache and evicting the inputs
// (256 MB, re-read every graph replay); nt stores keep L3 for the inputs.

#define TB_W 128           // output tile width
#define TB_H 16            // output tile height
#define SX   136           // staged width:  TB_W + 8 (16B-aligned halo)
#define SY   20            // staged height: TB_H + 4
#define NV4  (SX / 4)      // 34 float4 per staged row
#define NSTG (SY * NV4)    // 680
#define HX   130           // h region width  (TB_W + 2)
#define HY   18            // h region height (TB_H + 2)
#define NH   (HX * HY)     // 2340 h points

__global__ __launch_bounds__(256) void fused_mconv2(
    const float* __restrict__ x, const int* __restrict__ mask,
    const float* __restrict__ w1p, const float* __restrict__ b1p,
    const float* __restrict__ w2p, const float* __restrict__ b2p,
    float* __restrict__ out, int H, int W)
{
    __shared__ float s_xm[SY][SX];   // x*m over halo-2 region
    __shared__ float s_hm[SY][SX];   // stage: m; after conv1: enc(h,m)

    const int tid  = threadIdx.y * 64 + threadIdx.x;     // block (64,4)
    const int c0   = blockIdx.x * TB_W;
    const int row0 = blockIdx.y * TB_H;
    const size_t plane = (size_t)H * W;
    const float* xb = x    + (size_t)blockIdx.z * plane;
    const int*   mb = mask + (size_t)blockIdx.z * plane;
    float*       ob = out  + (size_t)blockIdx.z * plane;

    float W1[9], W2[9];
    #pragma unroll
    for (int i = 0; i < 9; ++i) { W1[i] = w1p[i]; W2[i] = w2p[i]; }
    const float B1 = b1p[0], B2 = b2p[0];

    // ---- stage: x*m and m, float4/int4 vector loads, origin (row0-2, c0-4) ----
    for (int idx = tid; idx < NSTG; idx += 256) {
        const int row  = idx / NV4;
        const int col4 = idx - row * NV4;
        const int r = row0 - 2 + row;
        const int c = c0 - 4 + (col4 << 2);
        float4 xm = make_float4(0.f, 0.f, 0.f, 0.f);
        float4 mm = make_float4(0.f, 0.f, 0.f, 0.f);
        if (r >= 0 && r < H && c >= 0 && c < W) {   // c%4==0, W%4==0 -> all-or-nothing
            const size_t g = (size_t)r * W + c;
            const float4 xv = *reinterpret_cast<const float4*>(xb + g);
            const int4   mi = *reinterpret_cast<const int4*>(mb + g);
            mm = make_float4((float)mi.x, (float)mi.y, (float)mi.z, (float)mi.w);
            xm = make_float4(xv.x * mm.x, xv.y * mm.y, xv.z * mm.z, xv.w * mm.w);
        }
        *reinterpret_cast<float4*>(&s_xm[row][col4 << 2]) = xm;
        *reinterpret_cast<float4*>(&s_hm[row][col4 << 2]) = mm;
    }
    __syncthreads();

    // ---- conv1: enc = m ? relu(conv(x*m)+b1) : -1, over 130x18 h region ----
    for (int idx = tid; idx < NH; idx += 256) {
        const int hrow = idx / HX;
        const int hcol = idx - hrow * HX;
        const float m = s_hm[hrow + 1][hcol + 3];
        float acc = B1;
        #pragma unroll
        for (int di = 0; di < 3; ++di)
            #pragma unroll
            for (int dj = 0; dj < 3; ++dj)
                acc += W1[di * 3 + dj] * s_xm[hrow + di][hcol + 2 + dj];
        const float h = acc > 0.f ? acc : 0.f;
        s_hm[hrow + 1][hcol + 3] = (m > 0.5f) ? h : -1.0f;
    }
    __syncthreads();

    // ---- conv2: column-per-lane register rolling, conflict-free reads ----
    {
        const int j     = tid & 127;        // output column
        const int strip = tid >> 7;         // 0..1
        const int i0    = strip * (TB_H / 2);
        float P = 0.f, Q = 0.f, cm = 0.f;
        #pragma unroll
        for (int t = 1; t <= TB_H / 2 + 2; ++t) {
            const int s = i0 + t;
            const float* rowp = &s_hm[s][0];
            const float t0 = rowp[j + 3];
            const float t1 = rowp[j + 4];
            const float t2 = rowp[j + 5];
            const float r0 = t0 > 0.f ? t0 : 0.f;
            const float r1 = t1 > 0.f ? t1 : 0.f;
            const float r2 = t2 > 0.f ? t2 : 0.f;
            const float d0 = W2[0] * r0 + W2[1] * r1 + W2[2] * r2;
            const float d1 = W2[3] * r0 + W2[4] * r1 + W2[5] * r2;
            const float d2 = W2[6] * r0 + W2[7] * r1 + W2[8] * r2;
            if (t >= 3) {
                const int i = s - 3;
                const float v = (cm >= 0.f) ? (Q + d2 + B2) : 0.f;
                __builtin_nontemporal_store(
                    v, ob + (size_t)(row0 + i) * W + (c0 + j));
            }
            Q  = P + d1;
            P  = d0;
            cm = t1;
        }
    }
}

extern "C" void kernel_launch(void* const* d_in, const int* in_sizes, int n_in,
                              void* d_out, int out_size, void* d_ws, size_t ws_size,
                              hipStream_t stream) {
    const float* x    = (const float*)d_in[0];
    const int*   mask = (const int*)  d_in[1];
    const float* w1   = (const float*)d_in[2];
    const float* b1   = (const float*)d_in[3];
    const float* w2   = (const float*)d_in[4];
    const float* b2   = (const float*)d_in[5];
    float*       out  = (float*)d_out;

    const int H = 2048, W = 2048;
    const int B = in_sizes[0] / (H * W);

    dim3 block(64, 4, 1);
    dim3 grid(W / TB_W, H / TB_H, B);   // 16 x 128 x 8
    hipLaunchKernelGGL(fused_mconv2, grid, block, 0, stream,
                       x, mask, w1, b1, w2, b2, out, H, W);
}